// Round 7
// baseline (248.645 us; speedup 1.0000x reference)
//
#include <hip/hip_runtime.h>
#include <stdint.h>
#include <stddef.h>

// Problem constants (B=2,S=2048,D=1024,H=16,HD=64)
#define SCALE_LOG2E 11.541560327111707f   // 8 * log2(e): folded into Q projection
#define E8 4194304                        // 4096*1024 plane (elements)
#define M1 1048576                        // 1024*1024 plane
#define NROW 65536                        // B*H*S rows

typedef __attribute__((ext_vector_type(8))) _Float16 f16x8;
typedef __attribute__((ext_vector_type(4))) _Float16 f16x4;
typedef __attribute__((ext_vector_type(4))) float f32x4;

#if __has_builtin(__builtin_amdgcn_exp2f)
#define EXP2F(x) __builtin_amdgcn_exp2f(x)
#else
#define EXP2F(x) exp2f(x)
#endif

__device__ __forceinline__ f32x4 mfma_f16(f16x8 a, f16x8 b, f32x4 c) {
  return __builtin_amdgcn_mfma_f32_16x16x32_f16(a, b, c, 0, 0, 0);
}

// Legacy 16x16x16 f16 MFMA: B-operand layout k = qd*4 + j matches the
// 16x16 C-layout row = qd*4 + r, so QK^T scores feed PV directly (no LDS, no shuffles).
__device__ __forceinline__ f32x4 mfma16_f16(f16x4 a, f16x4 b, f32x4 c) {
  return __builtin_amdgcn_mfma_f32_16x16x16f16(a, b, c, 0, 0, 0);
}

// async global->LDS, 16B per lane. LDS dest is wave-uniform base + lane*16.
__device__ __forceinline__ void async16(const void* g, void* lds) {
  __builtin_amdgcn_global_load_lds(
      (const __attribute__((address_space(1))) unsigned int*)g,
      (__attribute__((address_space(3))) unsigned int*)lds, 16, 0, 0);
}

__device__ __forceinline__ f16x8 cvt8(float4 a, float4 b) {
  return f16x8{(_Float16)a.x, (_Float16)a.y, (_Float16)a.z, (_Float16)a.w,
               (_Float16)b.x, (_Float16)b.y, (_Float16)b.z, (_Float16)b.w};
}

// ---------------- fp32 -> fp16 conversion, W planes only ----------------
// X (query/key/value) conversion is fused into gemm_qkv's A reg-staging.
// 1024 blocks x 256 thr x 4 float4 = 4 x M1 elements.
__global__ void prep_w(const float* __restrict__ wq, const float* __restrict__ wk,
                       const float* __restrict__ wv, const float* __restrict__ wo,
                       _Float16* __restrict__ Wf) {
  const int gid = blockIdx.x;
  const int z = gid >> 8;                // 256 blocks per plane
  const float* src = (z == 0) ? wq : (z == 1) ? wk : (z == 2) ? wv : wo;
  _Float16* dst = Wf + (size_t)z * M1;
  const int i = (gid & 255) * 1024 + threadIdx.x;
#pragma unroll
  for (int off = 0; off < 1024; off += 256) {
    float4 x = ((const float4*)src)[i + off];
    f16x4 h = {(_Float16)x.x, (_Float16)x.y, (_Float16)x.z, (_Float16)x.w};
    ((f16x4*)dst)[i + off] = h;
  }
}

// ---------------- merged Q/K/V projection: fp16 GEMM, A fused-converted from fp32 ----------------
// z=0: Q (query, bias bq, *SCALE_LOG2E) -> [B,H,S,HD] at Of
// z=1: K (key,   bias bk)               -> [B,H,S,HD] at Of+E8
// z=2: V (value, bias bv)               -> V^T [B,H,HD,S] at Of+2*E8
// grid (32, 8, 3): x = m-tile (XCD-clustering: the 8 n-blocks sharing an A-panel have
// flat id m + 32n + 256z === m (mod 8) -> same XCD L2 -> A fetched once, not 8x).
// A staging (T14 split): global fp32 loads issued right after the barrier, cvt +
// ds_write_b128 after the MFMA block (HBM latency hides under compute). This fuses
// the former prep_all X pass (50MB read + 25MB write + 25MB re-read) into the GEMM.
// B (weights) stays on async16 DMA from the pre-converted Wf.
__global__ __launch_bounds__(256, 3) void gemm_qkv(
    const float* __restrict__ q32, const float* __restrict__ k32,
    const float* __restrict__ v32,
    const _Float16* __restrict__ Wf,    // 4 planes stride M1 (planes 0..2 used here)
    const float* __restrict__ bq, const float* __restrict__ bk,
    const float* __restrict__ bv,
    _Float16* __restrict__ Of)
{
  __shared__ _Float16 SMEM[16384];      // staging dbuf (2x4096 A + 2x4096 B) / epilogue Ct
  _Float16* LA = SMEM;                  // [2][4096]
  _Float16* LB = SMEM + 8192;           // [2][4096]
  const int z = blockIdx.z;
  const int tid = threadIdx.x;
  const int lane = tid & 63;
  const int wv = tid >> 6;
  const int wm = wv >> 1, wn = wv & 1;
  const int rl = lane & 15, qd = lane >> 4;
  const int m0 = blockIdx.x * 128, n0 = blockIdx.y * 128;   // x=m, y=n (XCD cluster)

  const float* A32 = (z == 0) ? q32 : (z == 1) ? k32 : v32;
  const _Float16* W0 = Wf + (size_t)z * M1;
  const float* bias = (z == 0) ? bq : (z == 1) ? bk : bv;

  f32x4 acc[4][4];
#pragma unroll
  for (int i = 0; i < 4; i++)
#pragma unroll
    for (int j = 0; j < 4; j++) acc[i][j] = f32x4{0.f, 0.f, 0.f, 0.f};

  const int srow = wv * 32 + (lane >> 2);
  const int scol = (lane & 3) * 8;

  // B: async16 DMA (dest byte = base + lane*16, linear row-major [128][32])
  auto stageB = [&](int k0, int buf) {
    const _Float16* gb = W0 + (size_t)(n0 + srow) * 1024 + k0 + scol;
    async16(gb, &LB[buf * 4096 + wv * 1024]);
    async16(gb + 16 * 1024, &LB[buf * 4096 + wv * 1024 + 512]);
  };
  // A: fp32 global loads into regs (issue early)
  auto loadA = [&](int k0, float4* ar) {
    const float* ga = A32 + (size_t)(m0 + srow) * 1024 + k0 + scol;
    ar[0] = *(const float4*)(ga);
    ar[1] = *(const float4*)(ga + 4);
    ar[2] = *(const float4*)(ga + 16 * 1024);
    ar[3] = *(const float4*)(ga + 16 * 1024 + 4);
  };
  // A: cvt + ds_write at the same offsets async16 would have used (write late)
  auto writeA = [&](int buf, const float4* ar) {
    *(f16x8*)&LA[buf * 4096 + wv * 1024 + lane * 8] = cvt8(ar[0], ar[1]);
    *(f16x8*)&LA[buf * 4096 + wv * 1024 + 512 + lane * 8] = cvt8(ar[2], ar[3]);
  };

  float4 ar[4];
  loadA(0, ar);
  stageB(0, 0);
  writeA(0, ar);
  for (int t = 0; t < 32; t++) {
    const int buf = t & 1;
    __syncthreads();                          // B DMA(t) drained; A(t) writes visible
    if (t + 1 < 32) {
      loadA((t + 1) * 32, ar);                // issue early: hides under MFMA below
      stageB((t + 1) * 32, buf ^ 1);
    }
    f16x8 af[4], bfr[4];
#pragma unroll
    for (int i = 0; i < 4; i++) af[i] = *(const f16x8*)&LA[buf * 4096 + (wm * 64 + i * 16 + rl) * 32 + qd * 8];
#pragma unroll
    for (int j = 0; j < 4; j++) bfr[j] = *(const f16x8*)&LB[buf * 4096 + (wn * 64 + j * 16 + rl) * 32 + qd * 8];
#pragma unroll
    for (int i = 0; i < 4; i++)
#pragma unroll
      for (int j = 0; j < 4; j++) acc[i][j] = mfma_f16(af[i], bfr[j], acc[i][j]);
    if (t + 1 < 32) writeA(buf ^ 1, ar);      // write late: vmcnt wait lands here
  }

  if (z == 2) {
    // V^T epilogue: Vt[b,h,e,s], 4 contiguous s per store
#pragma unroll
    for (int j = 0; j < 4; j++) {
      const int nn = n0 + wn * 64 + j * 16 + rl;
      const float bj = bias[nn];
      const int hh = nn >> 6, e = nn & 63;
#pragma unroll
      for (int i = 0; i < 4; i++) {
        const int mm = m0 + wm * 64 + i * 16 + qd * 4;
        const int b = mm >> 11, s = mm & 2047;
        f16x4 pk = {(_Float16)(acc[i][j][0] + bj), (_Float16)(acc[i][j][1] + bj),
                    (_Float16)(acc[i][j][2] + bj), (_Float16)(acc[i][j][3] + bj)};
        *(f16x4*)(Of + 2 * (size_t)E8 + (((size_t)((b * 16 + hh) * 64 + e)) << 11) + s) = pk;
      }
    }
  } else {
    // LDS-transposed coalesced epilogue: Ct[128][128] with qd-xor column swizzle
    const float scl = (z == 0) ? SCALE_LOG2E : 1.0f;
    _Float16* base = Of + (size_t)z * E8;
    __syncthreads();                          // staging LDS now free
#pragma unroll
    for (int j = 0; j < 4; j++) {
      const int nl = wn * 64 + j * 16 + rl;
      const float bj = bias[n0 + nl];
#pragma unroll
      for (int i = 0; i < 4; i++) {
        const int ml = wm * 64 + i * 16 + qd * 4;
        const int np = nl ^ (qd << 4);        // (m>>2)&3 == qd here
#pragma unroll
        for (int r = 0; r < 4; r++)
          SMEM[(ml + r) * 128 + np] = (_Float16)((acc[i][j][r] + bj) * scl);
      }
    }
    __syncthreads();
#pragma unroll
    for (int it2 = 0; it2 < 8; it2++) {
      const int m = (it2 * 256 + tid) >> 4;   // 0..127
      const int col8 = (tid & 15) * 8;
      const int np = col8 ^ (((m >> 2) & 3) << 4);
      f16x8 vrow = *(const f16x8*)&SMEM[m * 128 + np];
      const int sg = m0 + m;
      const int b = sg >> 11, s = sg & 2047;
      const int nn = n0 + col8;
      const int hh = nn >> 6, e = nn & 63;
      *(f16x8*)(base + (((size_t)((b * 16 + hh) * 2048 + s)) << 6) + e) = vrow;
    }
  }
}

// ---------------- flash attention v12: v7 core (best measured) + bh-XCD clustering ----------------
// grid (32, 16, 2): x = bh, y = q-block (128 rows), z = kv half (1024 keys).
// Flat id === bh (mod 32) -> all 32 blocks sharing one head's K/V land on XCD bh%8
// (4 bh/XCD x 512KB K/V = 2MB <= 4MB L2) -> K/V L2-resident (measured: FETCH 69.7->12.3MB).
// Core is v7 verbatim (65.5us measured). Known 2-way PV b64 conflict accepted.
__global__ __launch_bounds__(256, 4) void attn_kernel(
    const _Float16* __restrict__ Qb,   // [B,H,S,HD], pre-scaled by 8*log2e
    const _Float16* __restrict__ Kb,   // [B,H,S,HD]
    const _Float16* __restrict__ Vt,   // [B,H,HD,S]
    float* __restrict__ Op,            // [2][NROW][64] f32 partial O^T (unnormalized)
    float2* __restrict__ ML)           // [2][NROW] (m, l)
{
  __shared__ _Float16 Ks[2][4096];     // dbuf [64 keys][64 d], xor-swizzled 16B chunks
  __shared__ _Float16 Vs[2][4096];     // dbuf [64 d][64 keys], same swizzle
  const int tid = threadIdx.x;
  const int lane = tid & 63;
  const int wv = tid >> 6;
  const int rl = lane & 15, qd = lane >> 4;
  const int bh = blockIdx.x;
  const int half = blockIdx.z;
  const int kvb = half * 1024;
  const int q0 = blockIdx.y * 128 + wv * 32;

  // Q as B-operand fragments [mt][kk]
  f16x8 qf[2][2];
#pragma unroll
  for (int mt = 0; mt < 2; mt++)
#pragma unroll
    for (int kk = 0; kk < 2; kk++)
      qf[mt][kk] = *(const f16x8*)(Qb + ((size_t)bh * 2048 + q0 + mt * 16 + rl) * 64 +
                                   kk * 32 + qd * 8);

  float m_[2] = {-1e30f, -1e30f}, l_[2] = {0.f, 0.f};  // l_ per-lane partial
  f32x4 o[2][4];
#pragma unroll
  for (int mt = 0; mt < 2; mt++)
#pragma unroll
    for (int jt = 0; jt < 4; jt++) o[mt][jt] = f32x4{0.f, 0.f, 0.f, 0.f};

  // stage K and V tiles (8 KB each) via async DMA, 16B-chunk xor swizzle
  auto stage = [&](int kv, int buf) {
#pragma unroll
    for (int it = 0; it < 2; it++) {
      const int cI = it * 256 + tid;           // chunk index 0..511
      const int row = cI >> 3;
      const int c = (cI & 7) ^ (row & 7);
      const int dst = (it * 256 + wv * 64) * 8;
      async16(Kb + ((size_t)bh * 2048 + kv + row) * 64 + c * 8, &Ks[buf][dst]);
      async16(Vt + ((size_t)bh * 64 + row) * 2048 + kv + c * 8, &Vs[buf][dst]);
    }
  };

  stage(kvb, 0);

  for (int t = 0; t < 16; t++) {
    const int buf = t & 1;
    __syncthreads();                           // DMA(t) drained; all done reading buf^1
    if (t + 1 < 16) stage(kvb + (t + 1) * 64, buf ^ 1);

    // ---- QK^T (S^T): sc[mt][nt]; key = nt*16 + qd*4 + r, q = q0 + mt*16 + rl ----
    f32x4 sc[2][4];
#pragma unroll
    for (int mt = 0; mt < 2; mt++)
#pragma unroll
      for (int nt = 0; nt < 4; nt++) sc[mt][nt] = f32x4{0.f, 0.f, 0.f, 0.f};
    __builtin_amdgcn_s_setprio(1);
#pragma unroll
    for (int nt = 0; nt < 4; nt++) {
      const int ro = (nt * 16 + rl) * 64;
#pragma unroll
      for (int kk = 0; kk < 2; kk++) {
        const int cc = (((kk * 4 + qd) ^ (rl & 7)) << 3);
        f16x8 kh = *(const f16x8*)&Ks[buf][ro + cc];
#pragma unroll
        for (int mt = 0; mt < 2; mt++)
          sc[mt][nt] = mfma_f16(kh, qf[mt][kk], sc[mt][nt]);
      }
    }
    __builtin_amdgcn_s_setprio(0);

    // ---- online softmax (exp2 domain), defer-max (THR=8), pack -> PV B-frags ----
    f16x4 pf[2][4];
#pragma unroll
    for (int mt = 0; mt < 2; mt++) {
      // tree max over this lane's 16 scores
      float a0 = fmaxf(fmaxf(sc[mt][0][0], sc[mt][0][1]), fmaxf(sc[mt][0][2], sc[mt][0][3]));
      float a1 = fmaxf(fmaxf(sc[mt][1][0], sc[mt][1][1]), fmaxf(sc[mt][1][2], sc[mt][1][3]));
      float a2 = fmaxf(fmaxf(sc[mt][2][0], sc[mt][2][1]), fmaxf(sc[mt][2][2], sc[mt][2][3]));
      float a3 = fmaxf(fmaxf(sc[mt][3][0], sc[mt][3][1]), fmaxf(sc[mt][3][2], sc[mt][3][3]));
      float mloc = fmaxf(fmaxf(a0, a1), fmaxf(a2, a3));
      // row max across the 4 qd lanes sharing rl
      float mx = fmaxf(mloc, __shfl_xor(mloc, 16));
      mx = fmaxf(mx, __shfl_xor(mx, 32));
      const float mold = m_[mt];
      float mnew = mold;
      if (__any(mx > mold + 8.f)) {            // T13: rescale only on real growth
        mnew = fmaxf(mold, mx);                // per-row (lanes with mx<=mold keep mold)
        const float al = EXP2F(mold - mnew);   // 1.0 where unchanged
        l_[mt] *= al;
#pragma unroll
        for (int jt = 0; jt < 4; jt++)
#pragma unroll
          for (int r = 0; r < 4; r++) o[mt][jt][r] *= al;
        m_[mt] = mnew;
      }
      // p bounded by 2^8 (defer threshold), fine in f16
      float sm = 0.f;
#pragma unroll
      for (int nt = 0; nt < 4; nt++) {
        const float p0 = EXP2F(sc[mt][nt][0] - mnew);
        const float p1 = EXP2F(sc[mt][nt][1] - mnew);
        const float p2 = EXP2F(sc[mt][nt][2] - mnew);
        const float p3 = EXP2F(sc[mt][nt][3] - mnew);
        sm += (p0 + p1) + (p2 + p3);
        pf[mt][nt] = f16x4{(_Float16)p0, (_Float16)p1, (_Float16)p2, (_Float16)p3};
      }
      l_[mt] += sm;
    }

    // ---- PV: O^T += V^T · P^T via 16x16x16 (scores in-register, zero LDS) ----
    __builtin_amdgcn_s_setprio(1);
#pragma unroll
    for (int nt = 0; nt < 4; nt++) {
      const int cb = nt * 2 + (qd >> 1);       // V^T column chunk (8 f16) for this lane
#pragma unroll
      for (int jt = 0; jt < 4; jt++) {
        const int row = jt * 16 + rl;          // row&7 == rl&7
        f16x4 vvv = *(const f16x4*)&Vs[buf][row * 64 + ((cb ^ (rl & 7)) << 3) + (qd & 1) * 4];
        o[0][jt] = mfma16_f16(vvv, pf[0][nt], o[0][jt]);
        o[1][jt] = mfma16_f16(vvv, pf[1][nt], o[1][jt]);
      }
    }
    __builtin_amdgcn_s_setprio(0);
  }

  // epilogue: write partials (unnormalized). lane holds d = jt*16 + qd*4 + r.
#pragma unroll
  for (int mt = 0; mt < 2; mt++) {
    float lt = l_[mt] + __shfl_xor(l_[mt], 16);
    lt += __shfl_xor(lt, 32);
    const size_t row = (size_t)bh * 2048 + q0 + mt * 16 + rl;
    float* op = Op + ((size_t)half * NROW + row) * 64;
#pragma unroll
    for (int jt = 0; jt < 4; jt++)
      *(f32x4*)(op + jt * 16 + qd * 4) = o[mt][jt];
    if (qd == 0) ML[(size_t)half * NROW + row] = make_float2(m_[mt], lt);
  }
}

// ---------------- merge the two KV halves ----------------
// block 256 = 16 rows x 16 threads; thread handles 4 d.
__global__ void merge_kernel(const float* __restrict__ Op,
                             const float2* __restrict__ ML,
                             _Float16* __restrict__ Xo) {
  const int t = threadIdx.x;
  const int row = blockIdx.x * 16 + (t >> 4);
  const int d0 = (t & 15) * 4;
  const float2 ml1 = ML[row];
  const float2 ml2 = ML[NROW + row];
  const float m = fmaxf(ml1.x, ml2.x);
  const float w1 = EXP2F(ml1.x - m), w2 = EXP2F(ml2.x - m);
  const float inv = 1.0f / (ml1.y * w1 + ml2.y * w2);
  const float4 o1 = *(const float4*)(Op + (size_t)row * 64 + d0);
  const float4 o2 = *(const float4*)(Op + (size_t)NROW * 64 + (size_t)row * 64 + d0);
  const int bh = row >> 11, q = row & 2047;
  const int b = bh >> 4, hh = bh & 15;
  f16x4 pk = {(_Float16)((o1.x * w1 + o2.x * w2) * inv),
              (_Float16)((o1.y * w1 + o2.y * w2) * inv),
              (_Float16)((o1.z * w1 + o2.z * w2) * inv),
              (_Float16)((o1.w * w1 + o2.w * w2) * inv)};
  *(f16x4*)(Xo + ((size_t)(b * 2048 + q)) * 1024 + hh * 64 + d0) = pk;
}

// ---------------- output projection: 64x128 tile, dbuf, fp32 out ----------------
// grid (64, 8): x = m-tile (XCD-clustering: 8 n-blocks sharing an A-panel have
// flat id m + 64n === m (mod 8) -> same XCD L2).
__global__ __launch_bounds__(256, 2) void gemm_out(
    const _Float16* __restrict__ A0,
    const _Float16* __restrict__ W0,
    const float* __restrict__ bias,
    float* __restrict__ out)
{
  __shared__ _Float16 LA[2][2048];   // 64 x 32
  __shared__ _Float16 LB[2][4096];   // 128 x 32
  const int tid = threadIdx.x;
  const int lane = tid & 63;
  const int wv = tid >> 6;
  const int wm = wv >> 1, wn = wv & 1;
  const int rl = lane & 15, qd = lane >> 4;
  const int m0 = blockIdx.x * 64, n0 = blockIdx.y * 128;   // x=m, y=n (XCD cluster)

  f32x4 acc[2][4];
#pragma unroll
  for (int i = 0; i < 2; i++)
#pragma unroll
    for (int j = 0; j < 4; j++) acc[i][j] = f32x4{0.f, 0.f, 0.f, 0.f};

  auto stage = [&](int k0, int buf) {
    {  // A: 256 chunks, 1 per thread
      const int row = tid >> 2, c = tid & 3;
      async16(A0 + (size_t)(m0 + row) * 1024 + k0 + c * 8, &LA[buf][wv * 512]);
    }
#pragma unroll
    for (int it = 0; it < 2; it++) {  // B: 512 chunks, 2 per thread
      const int cI = it * 256 + tid;
      const int row = cI >> 2, c = cI & 3;
      async16(W0 + (size_t)(n0 + row) * 1024 + k0 + c * 8,
              &LB[buf][it * 2048 + wv * 512]);
    }
  };

  stage(0, 0);
  for (int t = 0; t < 32; t++) {
    const int buf = t & 1;
    __syncthreads();
    if (t + 1 < 32) stage((t + 1) * 32, buf ^ 1);
    f16x8 af[2], bfr[4];
#pragma unroll
    for (int i = 0; i < 2; i++) af[i] = *(const f16x8*)&LA[buf][(wm * 32 + i * 16 + rl) * 32 + qd * 8];
#pragma unroll
    for (int j = 0; j < 4; j++) bfr[j] = *(const f16x8*)&LB[buf][(wn * 64 + j * 16 + rl) * 32 + qd * 8];
#pragma unroll
    for (int i = 0; i < 2; i++)
#pragma unroll
      for (int j = 0; j < 4; j++) acc[i][j] = mfma_f16(af[i], bfr[j], acc[i][j]);
  }

#pragma unroll
  for (int j = 0; j < 4; j++) {
    const int nn = n0 + wn * 64 + j * 16 + rl;
    const float bj = bias[nn];
#pragma unroll
    for (int i = 0; i < 2; i++) {
      const int mm = m0 + wm * 32 + i * 16 + qd * 4;
#pragma unroll
      for (int r = 0; r < 4; r++)
        out[(size_t)(mm + r) * 1024 + nn] = acc[i][j][r] + bj;
    }
  }
}

// ---------------- launch ----------------
extern "C" void kernel_launch(void* const* d_in, const int* in_sizes, int n_in,
                              void* d_out, int out_size, void* d_ws, size_t ws_size,
                              hipStream_t stream) {
  const float* query = (const float*)d_in[0];
  const float* key   = (const float*)d_in[1];
  const float* value = (const float*)d_in[2];
  const float* Wq = (const float*)d_in[3];
  const float* bq = (const float*)d_in[4];
  const float* Wk = (const float*)d_in[5];
  const float* bk = (const float*)d_in[6];
  const float* Wv = (const float*)d_in[7];
  const float* bv = (const float*)d_in[8];
  const float* Wo = (const float*)d_in[9];
  const float* bo = (const float*)d_in[10];

  // workspace: f16 region + f32 partials (Xf slot retained but unused; layout unchanged)
  _Float16* ws = (_Float16*)d_ws;
  _Float16* Wf = ws + 3 * (size_t)E8;         // 4*M1: Wq,Wk,Wv,Wo fp16
  _Float16* Qh = Wf + 4 * (size_t)M1;         // E8 [B,H,S,HD] (pre-scaled)
  _Float16* Kh = Qh + (size_t)E8;             // E8 [B,H,S,HD]
  _Float16* Vt = Kh + (size_t)E8;             // E8 [B,H,HD,S]
  _Float16* Xa = Vt + (size_t)E8;             // E8 [B,S,D]
  float*    Op = (float*)(Xa + (size_t)E8);   // [2][NROW][64] f32
  float2*   ML = (float2*)(Op + 2 * (size_t)NROW * 64);  // [2][NROW]

  prep_w<<<1024, 256, 0, stream>>>(Wq, Wk, Wv, Wo, Wf);
  gemm_qkv<<<dim3(32, 8, 3), 256, 0, stream>>>(query, key, value, Wf, bq, bk, bv, Qh);
  attn_kernel<<<dim3(32, 16, 2), 256, 0, stream>>>(Qh, Kh, Vt, Op, ML);
  merge_kernel<<<4096, 256, 0, stream>>>(Op, ML, Xa);
  gemm_out<<<dim3(64, 8), 256, 0, stream>>>(Xa, Wf + 3 * (size_t)M1, bo, (float*)d_out);
}